// Round 5
// baseline (1277.817 us; speedup 1.0000x reference)
//
#include <hip/hip_runtime.h>
#include <math.h>

// LSTMEncoder: N=2048 rows, T=128, H=256. Wave-autonomous design:
// 2048 waves (256 blocks x 8), each owns 16 rows x 64 gate-cols (16 h-cols x 4 gates).
// W slice (incl. folded x-path as 9th K-tile) persistent in VGPRs (144/lane).
// h exchanged via bf16 hx[2][2048][256] at the Infinity Cache (sc0sc1), with
// per-wave byte flags (plain stores, no atomics, no __syncthreads anywhere).
// Gate order i,f,g,o ; unit (rg, u): rg=rows rg*64..+63, u=(cg,wm): cg=u>>2 col
// group (16 cols x 4 gates), wm=u&3 row stripe (16 rows).

#define TT 128
#define NH 256

typedef __attribute__((ext_vector_type(4))) float f32x4;
typedef __attribute__((ext_vector_type(8))) short s16x8;
typedef union { uint4 u; s16x8 s; } frag_u;

// ws layout (bytes):
//   [0, 589824)            wsW  : 576 frags (16cg x 4q x 9kt) x 64 lanes x 16B
//   [589824, 2686976)      hx   : [2][2048][256] bf16
//   [2686976, 2689024)     flags: [32 rg][4 wm][16 cg] u8
#define OFF_HX    589824
#define OFF_FLAGS 2686976

__device__ __forceinline__ unsigned short f2bf(float x) {
    unsigned u = __float_as_uint(x);
    return (unsigned short)((u + 0x7FFFu + ((u >> 16) & 1u)) >> 16);
}

__global__ void prep(const float* __restrict__ W_emb, const float* __restrict__ b_emb,
                     const float* __restrict__ W_ih,  const float* __restrict__ W_hh,
                     const float* __restrict__ b_ih,  const float* __restrict__ b_hh,
                     unsigned short* __restrict__ wsW)
{
    int tid = blockIdx.x * 256 + threadIdx.x;   // 0..36863
    int l   = tid & 63;
    int fid = tid >> 6;          // 0..575
    int kt  = fid % 9;
    int ntg = fid / 9;           // cg*4+q
    int q   = ntg & 3;
    int cg  = ntg >> 2;
    int g   = q * 256 + cg * 16 + (l & 15);   // gate row
    union { unsigned short u16[8]; uint4 v; } pk;
    if (kt < 8) {
        int k0 = kt * 32 + (l >> 4) * 8;
        const float* src = &W_hh[g * 256 + k0];
        #pragma unroll
        for (int i = 0; i < 8; ++i) pk.u16[i] = f2bf(src[i]);
    } else {
        // folded x-path K-tile: [Wc[g][0..5], b_comb[g], 0...] at k-slots 0..7
        #pragma unroll
        for (int i = 0; i < 8; ++i) pk.u16[i] = 0;
        if ((l >> 4) == 0) {
            float accf[6] = {0.f, 0.f, 0.f, 0.f, 0.f, 0.f};
            float accb = 0.f;
            for (int e = 0; e < 256; ++e) {
                float wv = W_ih[g * 256 + e];
                accb += wv * b_emb[e];
                #pragma unroll
                for (int f = 0; f < 6; ++f) accf[f] += wv * W_emb[e * 6 + f];
            }
            #pragma unroll
            for (int f = 0; f < 6; ++f) pk.u16[f] = f2bf(accf[f]);
            pk.u16[6] = f2bf(accb + b_ih[g] + b_hh[g]);
            pk.u16[7] = 0;
        }
    }
    *reinterpret_cast<uint4*>(&wsW[(size_t)fid * 512 + l * 8]) = pk.v;
}

__device__ __forceinline__ float sigmoidf_(float x) { return 1.f / (1.f + __expf(-x)); }
__device__ __forceinline__ float tanhf_(float x) {
    float e = __expf(-2.f * fabsf(x));
    float r = (1.f - e) / (1.f + e);
    return copysignf(r, x);
}

__device__ __forceinline__ s16x8 pack_x(const float* xin, int arow, int t, int lg) {
    union { unsigned short u16[8]; uint4 q; s16x8 s; } pk;
    pk.q = (uint4){0u, 0u, 0u, 0u};
    if (lg == 0) {
        const float* xp = xin + ((size_t)arow * TT + t) * 6;
        #pragma unroll
        for (int f = 0; f < 6; ++f) pk.u16[f] = f2bf(xp[f]);
        pk.u16[6] = 0x3F80;  // 1.0 (bias slot)
    }
    return pk.s;
}

__global__ __launch_bounds__(512, 2)
void lstm_main(const float* __restrict__ xin, const unsigned short* __restrict__ wsW,
               float* __restrict__ out, unsigned short* __restrict__ hx,
               unsigned char* __restrict__ flags)
{
    const int tid = threadIdx.x;
    const int w   = tid >> 6, l = tid & 63;
    const int l16 = l & 15,  lg = l >> 4;
    const int bid = blockIdx.x;
    const int rg  = bid >> 3;                 // 0..31
    const int u   = (bid & 7) * 8 + w;        // 0..63
    const int cg  = u >> 2;                   // 0..15
    const int wm  = u & 3;                    // 0..3
    const int n0  = rg * 64;
    const int j   = cg * 16 + l16;            // global h col
    const int arow  = n0 + wm * 16 + l16;     // A-frag row
    const int crow0 = n0 + wm * 16 + lg * 4;  // C rows base

    // ---- persistent W fragments: 36 x s16x8 = 144 VGPR, loaded ONCE ----
    s16x8 Wf[4][9];
    #pragma unroll
    for (int q = 0; q < 4; ++q)
        #pragma unroll
        for (int kt = 0; kt < 9; ++kt)
            Wf[q][kt] = *reinterpret_cast<const s16x8*>(
                &wsW[(size_t)((cg * 4 + q) * 9 + kt) * 512 + l * 8]);

    unsigned char* myflag = &flags[rg * 64 + wm * 16 + cg];
    const unsigned char* pollp = &flags[rg * 64 + wm * 16 + l16];

    s16x8 xa = pack_x(xin, arow, 0, lg);
    float c_[4] = {0.f, 0.f, 0.f, 0.f};

    for (int t = 0; t < TT; ++t) {
        f32x4 acc[4];
        #pragma unroll
        for (int q = 0; q < 4; ++q) acc[q] = (f32x4){0.f, 0.f, 0.f, 0.f};

        if (t > 0) {
            // ---- poll the 16 producers of this wm-stripe (one 16B line) ----
            unsigned v; long it = 0;
            do {
                asm volatile("global_load_ubyte %0, %1, off sc0 sc1\n\t"
                             "s_waitcnt vmcnt(0)"
                             : "=v"(v) : "v"(pollp) : "memory");
                if (++it > (1L << 18)) break;   // fail loud, not hang
            } while (!__all((int)v >= t));

            // ---- A-frags straight from hx (IF) into registers ----
            const unsigned short* ab =
                hx + ((size_t)((t - 1) & 1) * 2048 + arow) * 256 + lg * 8;
            frag_u a0, a1, a2, a3, a4, a5, a6, a7;
            asm volatile(
                "global_load_dwordx4 %0, %8, off sc0 sc1\n\t"
                "global_load_dwordx4 %1, %8, off offset:64 sc0 sc1\n\t"
                "global_load_dwordx4 %2, %8, off offset:128 sc0 sc1\n\t"
                "global_load_dwordx4 %3, %8, off offset:192 sc0 sc1\n\t"
                "global_load_dwordx4 %4, %8, off offset:256 sc0 sc1\n\t"
                "global_load_dwordx4 %5, %8, off offset:320 sc0 sc1\n\t"
                "global_load_dwordx4 %6, %8, off offset:384 sc0 sc1\n\t"
                "global_load_dwordx4 %7, %8, off offset:448 sc0 sc1\n\t"
                "s_waitcnt vmcnt(0)"
                : "=v"(a0.u), "=v"(a1.u), "=v"(a2.u), "=v"(a3.u),
                  "=v"(a4.u), "=v"(a5.u), "=v"(a6.u), "=v"(a7.u)
                : "v"(ab) : "memory");

            #pragma unroll
            for (int q = 0; q < 4; ++q) {
                acc[q] = __builtin_amdgcn_mfma_f32_16x16x32_bf16(a0.s, Wf[q][0], acc[q], 0, 0, 0);
                acc[q] = __builtin_amdgcn_mfma_f32_16x16x32_bf16(a1.s, Wf[q][1], acc[q], 0, 0, 0);
                acc[q] = __builtin_amdgcn_mfma_f32_16x16x32_bf16(a2.s, Wf[q][2], acc[q], 0, 0, 0);
                acc[q] = __builtin_amdgcn_mfma_f32_16x16x32_bf16(a3.s, Wf[q][3], acc[q], 0, 0, 0);
                acc[q] = __builtin_amdgcn_mfma_f32_16x16x32_bf16(a4.s, Wf[q][4], acc[q], 0, 0, 0);
                acc[q] = __builtin_amdgcn_mfma_f32_16x16x32_bf16(a5.s, Wf[q][5], acc[q], 0, 0, 0);
                acc[q] = __builtin_amdgcn_mfma_f32_16x16x32_bf16(a6.s, Wf[q][6], acc[q], 0, 0, 0);
                acc[q] = __builtin_amdgcn_mfma_f32_16x16x32_bf16(a7.s, Wf[q][7], acc[q], 0, 0, 0);
            }
        }
        // x-path + bias via 9th K-tile
        #pragma unroll
        for (int q = 0; q < 4; ++q)
            acc[q] = __builtin_amdgcn_mfma_f32_16x16x32_bf16(xa, Wf[q][8], acc[q], 0, 0, 0);

        // prefetch next x while elementwise runs (cached loads)
        if (t + 1 < TT) xa = pack_x(xin, arow, t + 1, lg);

        // ---- lane-local elementwise ----
        float hn[4];
        #pragma unroll
        for (int r = 0; r < 4; ++r) {
            float gi = sigmoidf_(acc[0][r]);
            float gf = sigmoidf_(acc[1][r]);
            float gg = tanhf_  (acc[2][r]);
            float go = sigmoidf_(acc[3][r]);
            float cn = fmaf(gf, c_[r], gi * gg);
            c_[r] = cn;
            hn[r] = go * tanhf_(cn);
        }

        if (t < TT - 1) {
            // ---- publish h(t) bf16 -> hx slot t&1, drain, set flag ----
            unsigned short* hb = hx + ((size_t)(t & 1) * 2048 + crow0) * 256 + j;
            #pragma unroll
            for (int r = 0; r < 4; ++r) {
                unsigned hv = (unsigned)f2bf(hn[r]);
                asm volatile("global_store_short %0, %1, off sc0 sc1"
                             :: "v"(hb + (size_t)r * 256), "v"(hv) : "memory");
            }
            asm volatile("s_waitcnt vmcnt(0)" ::: "memory");
            if (l == 0) {
                unsigned fv = (unsigned)(t + 1);
                asm volatile("global_store_byte %0, %1, off sc0 sc1"
                             :: "v"(myflag), "v"(fv) : "memory");
            }
        }

        // ---- out stores (normal cached, off the critical chain) ----
        #pragma unroll
        for (int r = 0; r < 4; ++r)
            out[((size_t)(crow0 + r) * TT + t) * NH + j] = hn[r];
    }
}

extern "C" void kernel_launch(void* const* d_in, const int* in_sizes, int n_in,
                              void* d_out, int out_size, void* d_ws, size_t ws_size,
                              hipStream_t stream)
{
    const float* xin   = (const float*)d_in[0];
    const float* W_emb = (const float*)d_in[1];
    const float* b_emb = (const float*)d_in[2];
    const float* W_ih  = (const float*)d_in[3];
    const float* W_hh  = (const float*)d_in[4];
    const float* b_ih  = (const float*)d_in[5];
    const float* b_hh  = (const float*)d_in[6];
    float* out = (float*)d_out;

    unsigned short* wsW   = (unsigned short*)d_ws;
    unsigned short* hx    = (unsigned short*)((char*)d_ws + OFF_HX);
    unsigned char*  flags = (unsigned char*)((char*)d_ws + OFF_FLAGS);

    hipMemsetAsync(flags, 0, 2048, stream);
    prep<<<144, 256, 0, stream>>>(W_emb, b_emb, W_ih, W_hh, b_ih, b_hh, wsW);
    lstm_main<<<256, 512, 0, stream>>>(xin, wsW, out, hx, flags);
}